// Round 1
// baseline (286.844 us; speedup 1.0000x reference)
//
#include <hip/hip_runtime.h>
#include <math.h>

#define D 64
#define EPS 1e-12f

// Kernel A: inv_norm[i] = 1 / max(||H_i||_2, eps). One 64-lane wave per row.
__global__ void norm_kernel(const float* __restrict__ H,
                            float* __restrict__ inv_norm, int N) {
    int wid  = (blockIdx.x * blockDim.x + threadIdx.x) >> 6;
    int lane = threadIdx.x & 63;
    if (wid >= N) return;
    float v  = H[(size_t)wid * D + lane];
    float ss = v * v;
    #pragma unroll
    for (int off = 32; off > 0; off >>= 1)
        ss += __shfl_xor(ss, off, 64);
    if (lane == 0) {
        inv_norm[wid] = 1.0f / fmaxf(sqrtf(ss), EPS);
    }
}

// Kernel B: build row_ptr from the sorted row (dst) array.
// row_ptr[r] = first edge index e with row[e] >= r; row_ptr[N] = E.
__global__ void rowptr_kernel(const int* __restrict__ row,
                              int* __restrict__ row_ptr, int E, int N) {
    int e = blockIdx.x * blockDim.x + threadIdx.x;
    if (e >= E) return;
    int cur  = row[e];
    int prev = (e == 0) ? -1 : row[e - 1];
    for (int r = prev + 1; r <= cur; ++r) row_ptr[r] = e;
    if (e == E - 1) {
        for (int r = cur + 1; r <= N; ++r) row_ptr[r] = E;
    }
}

// Kernel C: fused score + online-softmax + aggregation.
// One wave per destination node; lane d owns feature dim d.
// score_e = (H[r] . H[c]) * inv_norm[r] * inv_norm[c]
// out[r]  = sum_e softmax(score)_e * H[c_e]     (raw H, per reference bspmm)
__global__ void agnn_kernel(const float* __restrict__ H,
                            const float* __restrict__ inv_norm,
                            const int* __restrict__ row_ptr,
                            const int* __restrict__ col,
                            float* __restrict__ out, int N) {
    int wid  = (blockIdx.x * blockDim.x + threadIdx.x) >> 6;
    int lane = threadIdx.x & 63;
    if (wid >= N) return;

    int start = row_ptr[wid];
    int end   = row_ptr[wid + 1];

    float hr = H[(size_t)wid * D + lane] * inv_norm[wid];  // Hn[r][lane]

    float m = -INFINITY;  // running max
    float l = 0.0f;       // running sum of exp
    float acc = 0.0f;     // running weighted feature accumulator (lane's dim)

    for (int e = start; e < end; ++e) {
        int c = col[e];
        float hc = H[(size_t)c * D + lane];   // raw H[c][lane] — reused below
        float s = hr * hc;
        #pragma unroll
        for (int off = 32; off > 0; off >>= 1)
            s += __shfl_xor(s, off, 64);      // full-wave dot reduce
        s *= inv_norm[c];                     // cosine similarity score

        float m_new = fmaxf(m, s);
        float scale = __expf(m - m_new);      // 0 when m == -inf (first edge)
        float p     = __expf(s - m_new);
        l   = l * scale + p;
        acc = acc * scale + p * hc;
        m   = m_new;
    }

    out[(size_t)wid * D + lane] = (l > 0.0f) ? acc / l : 0.0f;
}

extern "C" void kernel_launch(void* const* d_in, const int* in_sizes, int n_in,
                              void* d_out, int out_size, void* d_ws, size_t ws_size,
                              hipStream_t stream) {
    const float* H   = (const float*)d_in[0];
    const int*   row = (const int*)d_in[1];
    const int*   col = (const int*)d_in[2];
    float*       out = (float*)d_out;

    int N = in_sizes[0] / D;
    int E = in_sizes[1];

    float* inv_norm = (float*)d_ws;
    int*   row_ptr  = (int*)((char*)d_ws + (size_t)N * sizeof(float));

    // 4 waves (4 rows) per 256-thread block
    norm_kernel<<<(N + 3) / 4, 256, 0, stream>>>(H, inv_norm, N);
    rowptr_kernel<<<(E + 255) / 256, 256, 0, stream>>>(row, row_ptr, E, N);
    agnn_kernel<<<(N + 3) / 4, 256, 0, stream>>>(H, inv_norm, row_ptr, col, out, N);
}

// Round 3
// 157.144 us; speedup vs baseline: 1.8254x; 1.8254x over previous
//
#include <hip/hip_runtime.h>
#include <math.h>

#define D 64
#define EPS 1e-12f

// Kernel A: inv_norm[i] = 1/max(||H_i||,eps). 16 lanes x float4 per row.
__global__ void norm_kernel(const float4* __restrict__ H4,
                            float* __restrict__ inv_norm, int N) {
    int tid = blockIdx.x * blockDim.x + threadIdx.x;
    int r   = tid >> 4;
    int sub = tid & 15;
    if (r >= N) return;
    float4 v = H4[(size_t)r * 16 + sub];
    float ss = v.x * v.x + v.y * v.y + v.z * v.z + v.w * v.w;
    ss += __shfl_xor(ss, 1, 64);
    ss += __shfl_xor(ss, 2, 64);
    ss += __shfl_xor(ss, 4, 64);
    ss += __shfl_xor(ss, 8, 64);
    if (sub == 0) inv_norm[r] = 1.0f / fmaxf(sqrtf(ss), EPS);
}

// Kernel B: row_ptr from sorted dst array.
__global__ void rowptr_kernel(const int* __restrict__ row,
                              int* __restrict__ row_ptr, int E, int N) {
    int e = blockIdx.x * blockDim.x + threadIdx.x;
    if (e >= E) return;
    int cur  = row[e];
    int prev = (e == 0) ? -1 : row[e - 1];
    for (int r = prev + 1; r <= cur; ++r) row_ptr[r] = e;
    if (e == E - 1) {
        for (int r = cur + 1; r <= N; ++r) row_ptr[r] = E;
    }
}

// Kernel C: fused score + online softmax + aggregation.
// One wave per dst row. 4 groups of 16 lanes; group g handles edges
// start+g, start+g+4, ... with an independent online softmax; lane `sub`
// owns feature dims [4*sub, 4*sub+4) as a float4. Groups merged at the end.
__global__ __launch_bounds__(256) void agnn_kernel(
    const float* __restrict__ H,
    const float* __restrict__ inv_norm,
    const int* __restrict__ row_ptr,
    const int* __restrict__ col,
    float* __restrict__ out, int N) {
    int wid  = (blockIdx.x * blockDim.x + threadIdx.x) >> 6;
    int lane = threadIdx.x & 63;
    if (wid >= N) return;
    int g   = lane >> 4;
    int sub = lane & 15;

    int start = row_ptr[wid];
    int end   = row_ptr[wid + 1];

    const float4* H4 = (const float4*)H;
    float4 hr = H4[(size_t)wid * 16 + sub];
    float inr = inv_norm[wid];
    hr.x *= inr; hr.y *= inr; hr.z *= inr; hr.w *= inr;

    float  m = -INFINITY, l = 0.0f;
    float4 acc = {0.0f, 0.0f, 0.0f, 0.0f};

    // software pipeline: stage edge e's data while computing edge e-4
    int e = start + g;
    int   c_cur = 0;
    float in_cur = 0.0f;
    float4 hc_cur = {0, 0, 0, 0};
    if (e < end) {
        c_cur  = col[e];
        in_cur = inv_norm[c_cur];
        hc_cur = H4[(size_t)c_cur * 16 + sub];
    }

    for (; e < end; e += 4) {
        // issue next gather before the dependent reduce chain
        int    c_n = 0;
        float  in_n = 0.0f;
        float4 hc_n = {0, 0, 0, 0};
        if (e + 4 < end) {
            c_n  = col[e + 4];
            in_n = inv_norm[c_n];
            hc_n = H4[(size_t)c_n * 16 + sub];
        }

        float s = hr.x * hc_cur.x + hr.y * hc_cur.y +
                  hr.z * hc_cur.z + hr.w * hc_cur.w;
        s += __shfl_xor(s, 1, 64);
        s += __shfl_xor(s, 2, 64);
        s += __shfl_xor(s, 4, 64);
        s += __shfl_xor(s, 8, 64);
        s *= in_cur;

        float m_new  = fmaxf(m, s);
        float scale  = __expf(m - m_new);   // 0 on first edge (m = -inf)
        float p      = __expf(s - m_new);
        l = l * scale + p;
        acc.x = acc.x * scale + p * hc_cur.x;
        acc.y = acc.y * scale + p * hc_cur.y;
        acc.z = acc.z * scale + p * hc_cur.z;
        acc.w = acc.w * scale + p * hc_cur.w;
        m = m_new;

        hc_cur = hc_n; in_cur = in_n; c_cur = c_n;
    }

    // merge the 4 groups' (m, l, acc) via cross-group butterfly
    #pragma unroll
    for (int off = 16; off <= 32; off <<= 1) {
        float  m_o = __shfl_xor(m, off, 64);
        float  l_o = __shfl_xor(l, off, 64);
        float4 a_o;
        a_o.x = __shfl_xor(acc.x, off, 64);
        a_o.y = __shfl_xor(acc.y, off, 64);
        a_o.z = __shfl_xor(acc.z, off, 64);
        a_o.w = __shfl_xor(acc.w, off, 64);
        float m_new = fmaxf(m, m_o);
        float sa = (m   == -INFINITY) ? 0.0f : __expf(m   - m_new);
        float sb = (m_o == -INFINITY) ? 0.0f : __expf(m_o - m_new);
        l = l * sa + l_o * sb;
        acc.x = acc.x * sa + a_o.x * sb;
        acc.y = acc.y * sa + a_o.y * sb;
        acc.z = acc.z * sa + a_o.z * sb;
        acc.w = acc.w * sa + a_o.w * sb;
        m = m_new;
    }

    if (g == 0) {
        float invl = (l > 0.0f) ? 1.0f / l : 0.0f;
        float4 o;
        o.x = acc.x * invl; o.y = acc.y * invl;
        o.z = acc.z * invl; o.w = acc.w * invl;
        ((float4*)out)[(size_t)wid * 16 + sub] = o;
    }
}

extern "C" void kernel_launch(void* const* d_in, const int* in_sizes, int n_in,
                              void* d_out, int out_size, void* d_ws, size_t ws_size,
                              hipStream_t stream) {
    const float* H   = (const float*)d_in[0];
    const int*   row = (const int*)d_in[1];
    const int*   col = (const int*)d_in[2];
    float*       out = (float*)d_out;

    int N = in_sizes[0] / D;
    int E = in_sizes[1];

    float* inv_norm = (float*)d_ws;
    int*   row_ptr  = (int*)((char*)d_ws + (size_t)N * sizeof(float));

    norm_kernel<<<(N * 16 + 255) / 256, 256, 0, stream>>>((const float4*)H, inv_norm, N);
    rowptr_kernel<<<(E + 255) / 256, 256, 0, stream>>>(row, row_ptr, E, N);
    agnn_kernel<<<(N + 3) / 4, 256, 0, stream>>>(H, inv_norm, row_ptr, col, out, N);
}

// Round 5
// 149.788 us; speedup vs baseline: 1.9150x; 1.0491x over previous
//
#include <hip/hip_runtime.h>
#include <math.h>

#define D 64
#define EPS 1e-12f

// Fused prep: inv_norm (16 lanes x float4 per row) + row_ptr build.
// Both jobs are exactly N*16 == E == 1.6M threads here; norm's shuffle
// region is wave-aligned (N*16 % 64 == 0).
__global__ void prep_kernel(const float4* __restrict__ H4,
                            float* __restrict__ inv_norm,
                            const int* __restrict__ row,
                            int* __restrict__ row_ptr, int N, int E) {
    int t = blockIdx.x * blockDim.x + threadIdx.x;
    if (t < N * 16) {
        int r = t >> 4, sub = t & 15;
        float4 v = H4[(size_t)r * 16 + sub];
        float ss = v.x * v.x + v.y * v.y + v.z * v.z + v.w * v.w;
        ss += __shfl_xor(ss, 1, 64);
        ss += __shfl_xor(ss, 2, 64);
        ss += __shfl_xor(ss, 4, 64);
        ss += __shfl_xor(ss, 8, 64);
        if (sub == 0) inv_norm[r] = 1.0f / fmaxf(sqrtf(ss), EPS);
    }
    if (t < E) {
        int cur  = row[t];
        int prev = (t == 0) ? -1 : row[t - 1];
        for (int r = prev + 1; r <= cur; ++r) row_ptr[r] = t;
        if (t == E - 1) {
            for (int r = cur + 1; r <= N; ++r) row_ptr[r] = E;
        }
    }
}

// Fused score + softmax + aggregation, NO online-max: cosine scores are
// bounded in [-1,1], so exp(s) is always safe and softmax is shift-invariant.
// One wave per dst row; 4 groups of 16 lanes; each group processes 2 edges
// per iteration (8 edges in flight per wave) with a 1-deep prefetch pipeline.
// Lane `sub` owns feature dims [4*sub, 4*sub+4) as a float4.
__global__ __launch_bounds__(256) void agnn_kernel(
    const float* __restrict__ H,
    const float* __restrict__ inv_norm,
    const int* __restrict__ row_ptr,
    const int* __restrict__ col,
    float* __restrict__ out, int N) {
    int wid  = (blockIdx.x * blockDim.x + threadIdx.x) >> 6;
    int lane = threadIdx.x & 63;
    if (wid >= N) return;
    int g   = lane >> 4;
    int sub = lane & 15;

    int start = row_ptr[wid];
    int end   = row_ptr[wid + 1];

    const float4* H4 = (const float4*)H;
    float4 hr = H4[(size_t)wid * 16 + sub];
    float inr = inv_norm[wid];
    hr.x *= inr; hr.y *= inr; hr.z *= inr; hr.w *= inr;

    float  l = 0.0f;
    float4 acc = {0.0f, 0.0f, 0.0f, 0.0f};

    // current 2-edge chunk state (edges e, e+4 within this group's stream)
    int e = start + g;
    float4 h0 = {0, 0, 0, 0}, h1 = {0, 0, 0, 0};
    float in0 = 0.0f, in1 = 0.0f, v0 = 0.0f, v1 = 0.0f;
    if (e < end)     { int c = col[e];     in0 = inv_norm[c]; h0 = H4[(size_t)c * 16 + sub]; v0 = 1.0f; }
    if (e + 4 < end) { int c = col[e + 4]; in1 = inv_norm[c]; h1 = H4[(size_t)c * 16 + sub]; v1 = 1.0f; }

    for (; e < end; e += 8) {
        // prefetch next chunk before the dependent reduce chains
        float4 nh0 = {0, 0, 0, 0}, nh1 = {0, 0, 0, 0};
        float nin0 = 0.0f, nin1 = 0.0f, nv0 = 0.0f, nv1 = 0.0f;
        if (e + 8  < end) { int c = col[e + 8];  nin0 = inv_norm[c]; nh0 = H4[(size_t)c * 16 + sub]; nv0 = 1.0f; }
        if (e + 12 < end) { int c = col[e + 12]; nin1 = inv_norm[c]; nh1 = H4[(size_t)c * 16 + sub]; nv1 = 1.0f; }

        float s0 = hr.x * h0.x + hr.y * h0.y + hr.z * h0.z + hr.w * h0.w;
        float s1 = hr.x * h1.x + hr.y * h1.y + hr.z * h1.z + hr.w * h1.w;
        s0 += __shfl_xor(s0, 1, 64);  s1 += __shfl_xor(s1, 1, 64);
        s0 += __shfl_xor(s0, 2, 64);  s1 += __shfl_xor(s1, 2, 64);
        s0 += __shfl_xor(s0, 4, 64);  s1 += __shfl_xor(s1, 4, 64);
        s0 += __shfl_xor(s0, 8, 64);  s1 += __shfl_xor(s1, 8, 64);

        float p0 = v0 * __expf(s0 * in0);   // v=0 lanes contribute exactly 0
        float p1 = v1 * __expf(s1 * in1);
        l += p0 + p1;
        acc.x += p0 * h0.x + p1 * h1.x;
        acc.y += p0 * h0.y + p1 * h1.y;
        acc.z += p0 * h0.z + p1 * h1.z;
        acc.w += p0 * h0.w + p1 * h1.w;

        h0 = nh0; h1 = nh1; in0 = nin0; in1 = nin1; v0 = nv0; v1 = nv1;
    }

    // plain-sum merge across the 4 groups (softmax shift removed => commutative)
    #pragma unroll
    for (int off = 16; off <= 32; off <<= 1) {
        l     += __shfl_xor(l, off, 64);
        acc.x += __shfl_xor(acc.x, off, 64);
        acc.y += __shfl_xor(acc.y, off, 64);
        acc.z += __shfl_xor(acc.z, off, 64);
        acc.w += __shfl_xor(acc.w, off, 64);
    }

    if (g == 0) {
        float invl = (l > 0.0f) ? 1.0f / l : 0.0f;
        float4 o;
        o.x = acc.x * invl; o.y = acc.y * invl;
        o.z = acc.z * invl; o.w = acc.w * invl;
        ((float4*)out)[(size_t)wid * 16 + sub] = o;
    }
}

extern "C" void kernel_launch(void* const* d_in, const int* in_sizes, int n_in,
                              void* d_out, int out_size, void* d_ws, size_t ws_size,
                              hipStream_t stream) {
    const float* H   = (const float*)d_in[0];
    const int*   row = (const int*)d_in[1];
    const int*   col = (const int*)d_in[2];
    float*       out = (float*)d_out;

    int N = in_sizes[0] / D;
    int E = in_sizes[1];

    float* inv_norm = (float*)d_ws;
    int*   row_ptr  = (int*)((char*)d_ws + (size_t)N * sizeof(float));

    int prep_threads = (N * 16 > E) ? N * 16 : E;
    prep_kernel<<<(prep_threads + 255) / 256, 256, 0, stream>>>(
        (const float4*)H, inv_norm, row, row_ptr, N, E);
    agnn_kernel<<<(N + 3) / 4, 256, 0, stream>>>(H, inv_norm, row_ptr, col, out, N);
}

// Round 6
// 147.933 us; speedup vs baseline: 1.9390x; 1.0125x over previous
//
#include <hip/hip_runtime.h>
#include <math.h>

#define D 64
#define EPS 1e-12f

// Fused prep: inv_norm (16 lanes x float4 per row) + row_ptr build.
__global__ void prep_kernel(const float4* __restrict__ H4,
                            float* __restrict__ inv_norm,
                            const int* __restrict__ row,
                            int* __restrict__ row_ptr, int N, int E) {
    int t = blockIdx.x * blockDim.x + threadIdx.x;
    if (t < N * 16) {
        int r = t >> 4, sub = t & 15;
        float4 v = H4[(size_t)r * 16 + sub];
        float ss = v.x * v.x + v.y * v.y + v.z * v.z + v.w * v.w;
        ss += __shfl_xor(ss, 1, 64);
        ss += __shfl_xor(ss, 2, 64);
        ss += __shfl_xor(ss, 4, 64);
        ss += __shfl_xor(ss, 8, 64);
        if (sub == 0) inv_norm[r] = 1.0f / fmaxf(sqrtf(ss), EPS);
    }
    if (t < E) {
        int cur  = row[t];
        int prev = (t == 0) ? -1 : row[t - 1];
        for (int r = prev + 1; r <= cur; ++r) row_ptr[r] = t;
        if (t == E - 1) {
            for (int r = cur + 1; r <= N; ++r) row_ptr[r] = E;
        }
    }
}

// Fused score + softmax + aggregation. No online-max (cosine scores bounded
// in [-1,1] => exp always safe; softmax shift-invariant => plain sums).
// One wave per dst row; 4 groups of 16 lanes; group g owns edges
// start+g+4k; 2 edges per iteration. All steady-state loads are
// UNCONDITIONAL via index clamping to end-1; the while-guard (e+4 < end)
// guarantees both live slots are valid edges, so the body has no
// predication. At loop exit the pipeline regs hold edge e's data, which the
// <=1-edge tail reuses directly.
__global__ __launch_bounds__(256) void agnn_kernel(
    const float* __restrict__ H,
    const float* __restrict__ inv_norm,
    const int* __restrict__ row_ptr,
    const int* __restrict__ col,
    float* __restrict__ out, int N) {
    int wid  = (blockIdx.x * blockDim.x + threadIdx.x) >> 6;
    int lane = threadIdx.x & 63;
    if (wid >= N) return;
    int g   = lane >> 4;
    int sub = lane & 15;

    int start = row_ptr[wid];
    int end   = row_ptr[wid + 1];

    if (start >= end) {  // empty row: out must be zeros (d_out is poisoned)
        if (g == 0) {
            float4 z = {0.0f, 0.0f, 0.0f, 0.0f};
            ((float4*)out)[(size_t)wid * 16 + sub] = z;
        }
        return;
    }

    const float4* H4 = (const float4*)H;
    float4 hr = H4[(size_t)wid * 16 + sub];
    float inr = inv_norm[wid];
    hr.x *= inr; hr.y *= inr; hr.z *= inr; hr.w *= inr;

    float  l = 0.0f;
    float4 acc = {0.0f, 0.0f, 0.0f, 0.0f};

    int e  = start + g;
    int cl = end - 1;  // clamp index: always valid since start < end

    // unconditional clamped prologue (values used only if in-bounds)
    int c0 = col[min(e, cl)];
    int c1 = col[min(e + 4, cl)];
    float  in0 = inv_norm[c0],            in1 = inv_norm[c1];
    float4 h0  = H4[(size_t)c0 * 16 + sub], h1 = H4[(size_t)c1 * 16 + sub];

    while (e + 4 < end) {  // both slots (e, e+4) are valid edges
        // unconditional clamped prefetch of the next chunk
        int n0 = col[min(e + 8,  cl)];
        int n1 = col[min(e + 12, cl)];
        float  nin0 = inv_norm[n0],            nin1 = inv_norm[n1];
        float4 nh0  = H4[(size_t)n0 * 16 + sub], nh1 = H4[(size_t)n1 * 16 + sub];

        float s0 = hr.x * h0.x + hr.y * h0.y + hr.z * h0.z + hr.w * h0.w;
        float s1 = hr.x * h1.x + hr.y * h1.y + hr.z * h1.z + hr.w * h1.w;
        s0 += __shfl_xor(s0, 1, 64);  s1 += __shfl_xor(s1, 1, 64);
        s0 += __shfl_xor(s0, 2, 64);  s1 += __shfl_xor(s1, 2, 64);
        s0 += __shfl_xor(s0, 4, 64);  s1 += __shfl_xor(s1, 4, 64);
        s0 += __shfl_xor(s0, 8, 64);  s1 += __shfl_xor(s1, 8, 64);

        float p0 = __expf(s0 * in0);
        float p1 = __expf(s1 * in1);
        l += p0 + p1;
        acc.x += p0 * h0.x + p1 * h1.x;
        acc.y += p0 * h0.y + p1 * h1.y;
        acc.z += p0 * h0.z + p1 * h1.z;
        acc.w += p0 * h0.w + p1 * h1.w;

        h0 = nh0; h1 = nh1; in0 = nin0; in1 = nin1;
        e += 8;
    }

    // tail: at most one edge left per group; h0/in0 already hold its data
    if (e < end) {
        float s = hr.x * h0.x + hr.y * h0.y + hr.z * h0.z + hr.w * h0.w;
        s += __shfl_xor(s, 1, 64);
        s += __shfl_xor(s, 2, 64);
        s += __shfl_xor(s, 4, 64);
        s += __shfl_xor(s, 8, 64);
        float p = __expf(s * in0);
        l += p;
        acc.x += p * h0.x;
        acc.y += p * h0.y;
        acc.z += p * h0.z;
        acc.w += p * h0.w;
    }

    // plain-sum merge across the 4 groups
    #pragma unroll
    for (int off = 16; off <= 32; off <<= 1) {
        l     += __shfl_xor(l, off, 64);
        acc.x += __shfl_xor(acc.x, off, 64);
        acc.y += __shfl_xor(acc.y, off, 64);
        acc.z += __shfl_xor(acc.z, off, 64);
        acc.w += __shfl_xor(acc.w, off, 64);
    }

    if (g == 0) {
        float invl = 1.0f / l;  // start < end => l >= 4 * e^-1 > 0
        float4 o;
        o.x = acc.x * invl; o.y = acc.y * invl;
        o.z = acc.z * invl; o.w = acc.w * invl;
        ((float4*)out)[(size_t)wid * 16 + sub] = o;
    }
}

extern "C" void kernel_launch(void* const* d_in, const int* in_sizes, int n_in,
                              void* d_out, int out_size, void* d_ws, size_t ws_size,
                              hipStream_t stream) {
    const float* H   = (const float*)d_in[0];
    const int*   row = (const int*)d_in[1];
    const int*   col = (const int*)d_in[2];
    float*       out = (float*)d_out;

    int N = in_sizes[0] / D;
    int E = in_sizes[1];

    float* inv_norm = (float*)d_ws;
    int*   row_ptr  = (int*)((char*)d_ws + (size_t)N * sizeof(float));

    int prep_threads = (N * 16 > E) ? N * 16 : E;
    prep_kernel<<<(prep_threads + 255) / 256, 256, 0, stream>>>(
        (const float4*)H, inv_norm, row, row_ptr, N, E);
    agnn_kernel<<<(N + 3) / 4, 256, 0, stream>>>(H, inv_norm, row_ptr, col, out, N);
}

// Round 9
// 141.868 us; speedup vs baseline: 2.0219x; 1.0428x over previous
//
#include <hip/hip_runtime.h>
#include <math.h>

#define D 64
#define EPS 1e-12f

typedef _Float16 half4_t __attribute__((ext_vector_type(4)));

// Fused prep: inv_norm + fp16 copy of H (for the gather path) + row_ptr.
__global__ void prep_kernel(const float4* __restrict__ H4,
                            float* __restrict__ inv_norm,
                            half4_t* __restrict__ Hh,
                            const int* __restrict__ row,
                            int* __restrict__ row_ptr, int N, int E,
                            int do_conv) {
    int t = blockIdx.x * blockDim.x + threadIdx.x;
    if (t < N * 16) {
        int r = t >> 4, sub = t & 15;
        float4 v = H4[(size_t)r * 16 + sub];
        if (do_conv) {
            half4_t h;
            h[0] = (_Float16)v.x; h[1] = (_Float16)v.y;
            h[2] = (_Float16)v.z; h[3] = (_Float16)v.w;
            Hh[(size_t)r * 16 + sub] = h;
        }
        float ss = v.x * v.x + v.y * v.y + v.z * v.z + v.w * v.w;
        ss += __shfl_xor(ss, 1, 64);
        ss += __shfl_xor(ss, 2, 64);
        ss += __shfl_xor(ss, 4, 64);
        ss += __shfl_xor(ss, 8, 64);
        if (sub == 0) inv_norm[r] = 1.0f / fmaxf(sqrtf(ss), EPS);
    }
    if (t < E) {
        int cur  = row[t];
        int prev = (t == 0) ? -1 : row[t - 1];
        for (int r = prev + 1; r <= cur; ++r) row_ptr[r] = t;
        if (t == E - 1) {
            for (int r = cur + 1; r <= N; ++r) row_ptr[r] = E;
        }
    }
}

// Fused score + softmax + aggregation (round-6 structure, fp16 gathers).
// One wave per dst row; 4 groups of 16 lanes; 2 edges/group/iter; clamped
// unconditional prefetch. FP16: gathered H rows are 128 B (one cache line)
// and the gathered footprint halves -> higher L2 hit rate. hr stays fp32.
template <bool FP16>
__global__ __launch_bounds__(256) void agnn_kernel(
    const float* __restrict__ H,
    const half4_t* __restrict__ Hh,
    const float* __restrict__ inv_norm,
    const int* __restrict__ row_ptr,
    const int* __restrict__ col,
    float* __restrict__ out, int N) {
    int wid  = (blockIdx.x * blockDim.x + threadIdx.x) >> 6;
    int lane = threadIdx.x & 63;
    if (wid >= N) return;
    int g   = lane >> 4;
    int sub = lane & 15;

    int start = row_ptr[wid];
    int end   = row_ptr[wid + 1];

    if (start >= end) {  // empty row: out must be zeros (d_out is poisoned)
        if (g == 0) {
            float4 z = {0.0f, 0.0f, 0.0f, 0.0f};
            ((float4*)out)[(size_t)wid * 16 + sub] = z;
        }
        return;
    }

    const float4* H4 = (const float4*)H;

    auto load_row = [&](int c) -> float4 {
        if constexpr (FP16) {
            half4_t h = Hh[(size_t)c * 16 + sub];
            float4 f;
            f.x = (float)h[0]; f.y = (float)h[1];
            f.z = (float)h[2]; f.w = (float)h[3];
            return f;
        } else {
            return H4[(size_t)c * 16 + sub];
        }
    };

    float4 hr = H4[(size_t)wid * 16 + sub];  // exact fp32 query row
    float inr = inv_norm[wid];
    hr.x *= inr; hr.y *= inr; hr.z *= inr; hr.w *= inr;

    float  l = 0.0f;
    float4 acc = {0.0f, 0.0f, 0.0f, 0.0f};

    int e  = start + g;
    int cl = end - 1;  // clamp index: always valid since start < end

    int c0 = col[min(e, cl)];
    int c1 = col[min(e + 4, cl)];
    float  in0 = inv_norm[c0], in1 = inv_norm[c1];
    float4 h0  = load_row(c0),  h1 = load_row(c1);

    while (e + 4 < end) {  // both slots (e, e+4) are valid edges
        int n0 = col[min(e + 8,  cl)];
        int n1 = col[min(e + 12, cl)];
        float  nin0 = inv_norm[n0], nin1 = inv_norm[n1];
        float4 nh0  = load_row(n0),  nh1 = load_row(n1);

        float s0 = hr.x * h0.x + hr.y * h0.y + hr.z * h0.z + hr.w * h0.w;
        float s1 = hr.x * h1.x + hr.y * h1.y + hr.z * h1.z + hr.w * h1.w;
        s0 += __shfl_xor(s0, 1, 64);  s1 += __shfl_xor(s1, 1, 64);
        s0 += __shfl_xor(s0, 2, 64);  s1 += __shfl_xor(s1, 2, 64);
        s0 += __shfl_xor(s0, 4, 64);  s1 += __shfl_xor(s1, 4, 64);
        s0 += __shfl_xor(s0, 8, 64);  s1 += __shfl_xor(s1, 8, 64);

        float p0 = __expf(s0 * in0);
        float p1 = __expf(s1 * in1);
        l += p0 + p1;
        acc.x += p0 * h0.x + p1 * h1.x;
        acc.y += p0 * h0.y + p1 * h1.y;
        acc.z += p0 * h0.z + p1 * h1.z;
        acc.w += p0 * h0.w + p1 * h1.w;

        h0 = nh0; h1 = nh1; in0 = nin0; in1 = nin1;
        e += 8;
    }

    // tail: at most one edge left per group; h0/in0 already hold its data
    if (e < end) {
        float s = hr.x * h0.x + hr.y * h0.y + hr.z * h0.z + hr.w * h0.w;
        s += __shfl_xor(s, 1, 64);
        s += __shfl_xor(s, 2, 64);
        s += __shfl_xor(s, 4, 64);
        s += __shfl_xor(s, 8, 64);
        float p = __expf(s * in0);
        l += p;
        acc.x += p * h0.x;
        acc.y += p * h0.y;
        acc.z += p * h0.z;
        acc.w += p * h0.w;
    }

    // plain-sum merge across the 4 groups
    #pragma unroll
    for (int off = 16; off <= 32; off <<= 1) {
        l     += __shfl_xor(l, off, 64);
        acc.x += __shfl_xor(acc.x, off, 64);
        acc.y += __shfl_xor(acc.y, off, 64);
        acc.z += __shfl_xor(acc.z, off, 64);
        acc.w += __shfl_xor(acc.w, off, 64);
    }

    if (g == 0) {
        float invl = 1.0f / l;  // start < end => l > 0
        float4 o;
        o.x = acc.x * invl; o.y = acc.y * invl;
        o.z = acc.z * invl; o.w = acc.w * invl;
        ((float4*)out)[(size_t)wid * 16 + sub] = o;
    }
}

extern "C" void kernel_launch(void* const* d_in, const int* in_sizes, int n_in,
                              void* d_out, int out_size, void* d_ws, size_t ws_size,
                              hipStream_t stream) {
    const float* H   = (const float*)d_in[0];
    const int*   row = (const int*)d_in[1];
    const int*   col = (const int*)d_in[2];
    float*       out = (float*)d_out;

    int N = in_sizes[0] / D;
    int E = in_sizes[1];

    // ws layout: [Hh: N*128 B] [inv_norm: N*4 B] [row_ptr: (N+1)*4 B]
    size_t hh_bytes = (size_t)N * 16 * sizeof(half4_t);
    size_t need     = hh_bytes + (size_t)N * 4 + (size_t)(N + 1) * 4;
    bool   use_fp16 = ws_size >= need;

    half4_t* Hh;
    float*   inv_norm;
    if (use_fp16) {
        Hh       = (half4_t*)d_ws;
        inv_norm = (float*)((char*)d_ws + hh_bytes);
    } else {
        Hh       = (half4_t*)d_ws;  // unused
        inv_norm = (float*)d_ws;
    }
    int* row_ptr = (int*)(inv_norm + N);

    int prep_threads = (N * 16 > E) ? N * 16 : E;
    prep_kernel<<<(prep_threads + 255) / 256, 256, 0, stream>>>(
        (const float4*)H, inv_norm, Hh, row, row_ptr, N, E, use_fp16 ? 1 : 0);

    if (use_fp16) {
        agnn_kernel<true><<<(N + 3) / 4, 256, 0, stream>>>(
            H, Hh, inv_norm, row_ptr, col, out, N);
    } else {
        agnn_kernel<false><<<(N + 3) / 4, 256, 0, stream>>>(
            H, Hh, inv_norm, row_ptr, col, out, N);
    }
}

// Round 10
// 140.338 us; speedup vs baseline: 2.0440x; 1.0109x over previous
//
#include <hip/hip_runtime.h>
#include <math.h>

#define D 64
#define EPS 1e-12f
#define LOG2E 1.4426950408889634f

typedef _Float16 half4_t __attribute__((ext_vector_type(4)));

// Full 16-lane sum via DPP (pure VALU, no LDS pipe / lgkmcnt).
// Groups of 16 lanes == CDNA DPP rows. Coverage: ror4+ror8 collapse the
// mod-4 lane classes; quad_perm xor1/xor2 merge the 4 classes.
__device__ __forceinline__ float dpp_sum16(float s) {
    int x;
    x = __builtin_amdgcn_update_dpp(__float_as_int(s), __float_as_int(s),
                                    0x124, 0xf, 0xf, false);  // row_ror:4
    s += __int_as_float(x);
    x = __builtin_amdgcn_update_dpp(__float_as_int(s), __float_as_int(s),
                                    0x128, 0xf, 0xf, false);  // row_ror:8
    s += __int_as_float(x);
    x = __builtin_amdgcn_update_dpp(__float_as_int(s), __float_as_int(s),
                                    0xB1, 0xf, 0xf, false);   // quad_perm [1,0,3,2]
    s += __int_as_float(x);
    x = __builtin_amdgcn_update_dpp(__float_as_int(s), __float_as_int(s),
                                    0x4E, 0xf, 0xf, false);   // quad_perm [2,3,0,1]
    s += __int_as_float(x);
    return s;
}

// Fused prep: inv_norm + log2e-scaled inv_norm + fp16 copy of H + row_ptr.
__global__ void prep_kernel(const float4* __restrict__ H4,
                            float* __restrict__ inv_norm,
                            float* __restrict__ in_log,
                            half4_t* __restrict__ Hh,
                            const int* __restrict__ row,
                            int* __restrict__ row_ptr, int N, int E,
                            int do_conv) {
    int t = blockIdx.x * blockDim.x + threadIdx.x;
    if (t < N * 16) {
        int r = t >> 4, sub = t & 15;
        float4 v = H4[(size_t)r * 16 + sub];
        if (do_conv) {
            half4_t h;
            h[0] = (_Float16)v.x; h[1] = (_Float16)v.y;
            h[2] = (_Float16)v.z; h[3] = (_Float16)v.w;
            Hh[(size_t)r * 16 + sub] = h;
        }
        float ss = v.x * v.x + v.y * v.y + v.z * v.z + v.w * v.w;
        ss += __shfl_xor(ss, 1, 64);
        ss += __shfl_xor(ss, 2, 64);
        ss += __shfl_xor(ss, 4, 64);
        ss += __shfl_xor(ss, 8, 64);
        if (sub == 0) {
            float inv = 1.0f / fmaxf(sqrtf(ss), EPS);
            inv_norm[r] = inv;
            if (do_conv) in_log[r] = inv * LOG2E;
        }
    }
    if (t < E) {
        int cur  = row[t];
        int prev = (t == 0) ? -1 : row[t - 1];
        for (int r = prev + 1; r <= cur; ++r) row_ptr[r] = t;
        if (t == E - 1) {
            for (int r = cur + 1; r <= N; ++r) row_ptr[r] = E;
        }
    }
}

// Fused score + softmax + aggregation. Round-9 structure (fp16 gathers,
// clamped unconditional prefetch, 2 edges/group/iter) with:
//  - DPP 16-lane reduce (VALU-only; removes in-loop ds_swizzle/lgkm chains)
//  - u32 byte-offset addressing for all gathers
//  - invg pre-scaled by log2e in fp16 path => p = exp2f(s * invg), 1 mul less
template <bool FP16>
__global__ __launch_bounds__(256) void agnn_kernel(
    const float* __restrict__ H,
    const half4_t* __restrict__ Hh,
    const float* __restrict__ inv_norm,   // exact, for own row
    const float* __restrict__ invg,       // gathered: in_log (fp16) / inv_norm (fp32)
    const int* __restrict__ row_ptr,
    const int* __restrict__ col,
    float* __restrict__ out, int N) {
    int wid  = (blockIdx.x * blockDim.x + threadIdx.x) >> 6;
    int lane = threadIdx.x & 63;
    if (wid >= N) return;
    int g   = lane >> 4;
    int sub = lane & 15;

    int start = row_ptr[wid];
    int end   = row_ptr[wid + 1];

    if (start >= end) {  // empty row: out must be zeros (d_out is poisoned)
        if (g == 0) {
            float4 z = {0.0f, 0.0f, 0.0f, 0.0f};
            ((float4*)out)[(size_t)wid * 16 + sub] = z;
        }
        return;
    }

    const float4* H4 = (const float4*)H;
    const char* Hb   = (const char*)(FP16 ? (const void*)Hh : (const void*)H);
    const char* Ib   = (const char*)invg;
    const char* Cb   = (const char*)col;
    unsigned subo    = (unsigned)sub << (FP16 ? 3 : 4);

    auto ld_row = [&](int c) -> float4 {
        if constexpr (FP16) {
            half4_t h = *(const half4_t*)(Hb + (((unsigned)c << 7) + subo));
            float4 f;
            f.x = (float)h[0]; f.y = (float)h[1];
            f.z = (float)h[2]; f.w = (float)h[3];
            return f;
        } else {
            return *(const float4*)(Hb + (((unsigned)c << 8) + subo));
        }
    };
    auto ld_in  = [&](int c) -> float { return *(const float*)(Ib + ((unsigned)c << 2)); };
    auto ld_col = [&](int i) -> int   { return *(const int*)(Cb + ((unsigned)i << 2)); };
    auto edge_p = [&](float s, float in) -> float {
        if constexpr (FP16) return exp2f(s * in);   // in pre-scaled by log2e
        else                return __expf(s * in);
    };

    float4 hr = H4[(size_t)wid * 16 + sub];  // exact fp32 query row
    float inr = inv_norm[wid];
    hr.x *= inr; hr.y *= inr; hr.z *= inr; hr.w *= inr;

    float  l = 0.0f;
    float4 acc = {0.0f, 0.0f, 0.0f, 0.0f};

    int e  = start + g;
    int cl = end - 1;  // clamp index: always valid since start < end

    int c0 = ld_col(min(e, cl));
    int c1 = ld_col(min(e + 4, cl));
    float  in0 = ld_in(c0),  in1 = ld_in(c1);
    float4 h0  = ld_row(c0), h1  = ld_row(c1);

    while (e + 4 < end) {  // both slots (e, e+4) are valid edges
        int n0 = ld_col(min(e + 8,  cl));
        int n1 = ld_col(min(e + 12, cl));
        float  nin0 = ld_in(n0),  nin1 = ld_in(n1);
        float4 nh0  = ld_row(n0), nh1  = ld_row(n1);

        float s0 = hr.x * h0.x + hr.y * h0.y + hr.z * h0.z + hr.w * h0.w;
        float s1 = hr.x * h1.x + hr.y * h1.y + hr.z * h1.z + hr.w * h1.w;
        s0 = dpp_sum16(s0);
        s1 = dpp_sum16(s1);

        float p0 = edge_p(s0, in0);
        float p1 = edge_p(s1, in1);
        l += p0 + p1;
        acc.x += p0 * h0.x + p1 * h1.x;
        acc.y += p0 * h0.y + p1 * h1.y;
        acc.z += p0 * h0.z + p1 * h1.z;
        acc.w += p0 * h0.w + p1 * h1.w;

        h0 = nh0; h1 = nh1; in0 = nin0; in1 = nin1;
        e += 8;
    }

    // tail: at most one edge left per group; h0/in0 already hold its data
    if (e < end) {
        float s = hr.x * h0.x + hr.y * h0.y + hr.z * h0.z + hr.w * h0.w;
        s = dpp_sum16(s);
        float p = edge_p(s, in0);
        l += p;
        acc.x += p * h0.x;
        acc.y += p * h0.y;
        acc.z += p * h0.z;
        acc.w += p * h0.w;
    }

    // plain-sum merge across the 4 groups (cross-row: keep shfl)
    #pragma unroll
    for (int off = 16; off <= 32; off <<= 1) {
        l     += __shfl_xor(l, off, 64);
        acc.x += __shfl_xor(acc.x, off, 64);
        acc.y += __shfl_xor(acc.y, off, 64);
        acc.z += __shfl_xor(acc.z, off, 64);
        acc.w += __shfl_xor(acc.w, off, 64);
    }

    if (g == 0) {
        float invl = 1.0f / l;  // start < end => l > 0
        float4 o;
        o.x = acc.x * invl; o.y = acc.y * invl;
        o.z = acc.z * invl; o.w = acc.w * invl;
        ((float4*)out)[(size_t)wid * 16 + sub] = o;
    }
}

extern "C" void kernel_launch(void* const* d_in, const int* in_sizes, int n_in,
                              void* d_out, int out_size, void* d_ws, size_t ws_size,
                              hipStream_t stream) {
    const float* H   = (const float*)d_in[0];
    const int*   row = (const int*)d_in[1];
    const int*   col = (const int*)d_in[2];
    float*       out = (float*)d_out;

    int N = in_sizes[0] / D;
    int E = in_sizes[1];

    // ws layout (fp16): [Hh: N*128 B][inv_norm: N*4][in_log: N*4][row_ptr: (N+1)*4]
    size_t hh_bytes = (size_t)N * 16 * sizeof(half4_t);
    size_t need     = hh_bytes + (size_t)N * 8 + (size_t)(N + 1) * 4;
    bool   use_fp16 = ws_size >= need;

    half4_t* Hh;
    float*   inv_norm;
    float*   in_log;
    int*     row_ptr;
    if (use_fp16) {
        Hh       = (half4_t*)d_ws;
        inv_norm = (float*)((char*)d_ws + hh_bytes);
        in_log   = inv_norm + N;
        row_ptr  = (int*)(in_log + N);
    } else {
        Hh       = (half4_t*)d_ws;  // unused
        inv_norm = (float*)d_ws;
        in_log   = inv_norm;        // unused alias
        row_ptr  = (int*)(inv_norm + N);
    }

    int prep_threads = (N * 16 > E) ? N * 16 : E;
    prep_kernel<<<(prep_threads + 255) / 256, 256, 0, stream>>>(
        (const float4*)H, inv_norm, in_log, Hh, row, row_ptr, N, E,
        use_fp16 ? 1 : 0);

    if (use_fp16) {
        agnn_kernel<true><<<(N + 3) / 4, 256, 0, stream>>>(
            H, Hh, inv_norm, in_log, row_ptr, col, out, N);
    } else {
        agnn_kernel<false><<<(N + 3) / 4, 256, 0, stream>>>(
            H, Hh, inv_norm, inv_norm, row_ptr, col, out, N);
    }
}